// Round 19
// baseline (991.378 us; speedup 1.0000x reference)
//
#include <hip/hip_runtime.h>
#include <cstdint>
#include <cmath>

#define HW 128
#define NPIX (HW * HW)

typedef _Float16 half8 __attribute__((ext_vector_type(8)));
typedef _Float16 half4 __attribute__((ext_vector_type(4)));
typedef float floatx16 __attribute__((ext_vector_type(16)));
typedef unsigned long long u64;

__device__ __forceinline__ float sigf(float x) {
    return __builtin_amdgcn_rcpf(1.0f + __expf(-x));
}
__device__ __forceinline__ float tanhf_(float x) {
    float cx = fminf(fmaxf(x, -20.0f), 20.0f);
    float e2 = __expf(2.0f * cx);
    return (e2 - 1.0f) * __builtin_amdgcn_rcpf(e2 + 1.0f);
}

// Coherent h-load: relaxed agent-scope atomics (sc1 -> IF coherence point).
__device__ __forceinline__ half8 ld_coh(const _Float16* p) {
    union { u64 u[2]; half8 h; } cv;
    cv.u[0] = __hip_atomic_load((const u64*)p,
                                __ATOMIC_RELAXED, __HIP_MEMORY_SCOPE_AGENT);
    cv.u[1] = __hip_atomic_load((const u64*)p + 1,
                                __ATOMIC_RELAXED, __HIP_MEMORY_SCOPE_AGENT);
    return cv.h;
}

// device-coherent write-through stores (visible at IF; no dirty L2 lines)
__device__ __forceinline__ void st_coh8(_Float16* p, half4 v) {
    asm volatile("global_store_dwordx2 %0, %1, off sc0 sc1"
                 :: "v"(p), "v"(v) : "memory");
}
__device__ __forceinline__ void st_coh4(float* p, float v) {
    asm volatile("global_store_dword %0, %1, off sc0 sc1"
                 :: "v"(p), "v"(v) : "memory");
}

// Neighbor-group sync. 32 groups (8x4 of 16x32-px tiles); group g exchanges
// halo only with its <=9 Chebyshev neighbors. 8 blocks/group arrive (bump
// gcnt[g], monotonic, 64B-padded); lanes 0..8 of wave 0 poll neighbors for
// >= 8k. All relaxed agent atomics; vmcnt drain first publishes sc1 stores.
__device__ __forceinline__ void group_sync(unsigned* gcnt, int g,
                                           int gy, int gx, unsigned k)
{
    asm volatile("s_waitcnt vmcnt(0)" ::: "memory");
    __syncthreads();
    const int tid = threadIdx.x;
    if (tid == 0)
        __hip_atomic_fetch_add(gcnt + g * 16, 1u,
                               __ATOMIC_RELAXED, __HIP_MEMORY_SCOPE_AGENT);
    if (tid < 9) {
        int dy = tid / 3 - 1, dx = tid % 3 - 1;
        int gy2 = gy + dy, gx2 = gx + dx;
        if (gy2 >= 0 && gy2 < 8 && gx2 >= 0 && gx2 < 4) {
            const unsigned* p = gcnt + (gy2 * 4 + gx2) * 16;
            while (__hip_atomic_load(p, __ATOMIC_RELAXED,
                                     __HIP_MEMORY_SCOPE_AGENT) < 8u * k)
                __builtin_amdgcn_s_sleep(1);
        }
    }
    __syncthreads();
}

// ---------------------------------------------------------------------------
// Wave-specialized megakernel. 256 blocks x 1024 thr. Block: group (bid&31)
// = 16x32 px tile, s-slice = bid>>5 (gate rows s*32..s*32+31).
// Waves 0-7  (fam0): cell1(tau) + readout(tau-2). Waves 8-15 (fam1):
// cell2(tau-1). Each family: 8 waves x 2 px rows, rolling-buffer tap loop.
// Interval schedule (R15-verified): per tau: [fam0 cell1(tau) || fam1
// cell2(tau-1)]; readout(tau-2); GROUP_SYNC(tau+1).
// h(t) storage parity: t odd -> bufA, t even -> bufB (h0a/h1a zeroed = t=-1).
// LDS (161536 B): wlds 119808 | sbuf 2x19584 (1 slice/family) | wl 2304 |
// blds 256.
// ---------------------------------------------------------------------------
__global__ __launch_bounds__(1024, 4)
void mega(const _Float16* __restrict__ xh, const _Float16* __restrict__ WpG,
          const float* __restrict__ b0g, const float* __restrict__ b1g,
          const float* __restrict__ Wr, const float* __restrict__ br,
          _Float16* __restrict__ h0a, _Float16* __restrict__ h0b,
          _Float16* __restrict__ h1a, _Float16* __restrict__ h1b,
          float* __restrict__ y, unsigned* gcnt)
{
    extern __shared__ __align__(16) char dyn[];
    _Float16* wlds = (_Float16*)dyn;
    _Float16* sbuf = (_Float16*)(dyn + 119808);
    float*    wl   = (float*)(dyn + 158976);
    float*    blds = (float*)(dyn + 161280);

    const int tid = threadIdx.x;
    const int bid = blockIdx.x;
    const int s = bid >> 5, g = bid & 31;
    const int ggy = g >> 2, ggx = g & 3;
    const int y0 = ggy * 16, x0 = ggx * 32;

    const int lane = tid & 63;
    const int wv   = tid >> 6;
    const int fam  = wv >> 3;           // 0: cell1+readout, 1: cell2
    const int wf   = wv & 7;            // family-local wave -> row pair
    const int r0   = 2 * wf;
    const int cl   = lane & 31, l5 = lane >> 5;

    // one-time: weights (both cells) + readout weights + biases into LDS
    const half8* wsrc = (const half8*)(WpG + (size_t)s * 59904);
    for (int i = tid; i < 7488; i += 1024) ((half8*)wlds)[i] = wsrc[i];
    for (int i = tid; i < 576; i += 1024) wl[i] = Wr[i];
    if (tid < 64) {
        int cell = tid >> 5, gj = tid & 31;
        blds[tid] = (cell ? b1g : b0g)[(gj >> 3) * 64 + s * 8 + (gj & 7)];
    }
    const float brv = br[0];
    float cr[2][4] = {{0, 0, 0, 0}, {0, 0, 0, 0}};   // this thread's cell-c

    // ---- staging precompute: 2448 elems = 2 slices x (612 px x 2 chunks) ----
    const int ch16 = tid & 1;
    int spb[3], slo[3], fl[3];
    #pragma unroll
    for (int e0 = 0; e0 < 3; ++e0) {
        int e = tid + e0 * 1024;
        spb[e0] = -1; slo[e0] = -1; fl[e0] = 0;
        if (e < 2448) {
            int f  = (e >= 1224) ? 1 : 0;
            int es = e - f * 1224;
            int pc = es >> 1;
            int r = pc / 34, c = pc - r * 34;
            int gy = y0 - 1 + r, gx = x0 - 1 + c;
            slo[e0] = f * 9792 + (ch16 * 612 + pc) * 8;
            fl[e0]  = f;
            if (gy >= 0 && gy < HW && gx >= 0 && gx < HW)
                spb[e0] = (gy * HW + gx) * 64 + ch16 * 8;
        }
    }
    // ---- readout precompute (fam0 threads, tid<512): 800 elems ----
    const int ch8 = tid & 7;
    const int py0 = y0 + (s >> 2) * 8, px0 = x0 + (s & 3) * 8;
    int rpb[2], rlo[2];
    #pragma unroll
    for (int e0 = 0; e0 < 2; ++e0) {
        int e = tid + e0 * 512;
        rpb[e0] = -1; rlo[e0] = -1;
        if (tid < 512 && e < 800) {
            int pc = e >> 3;
            int r = pc / 10, c = pc - r * 10;
            int gy = py0 - 1 + r, gx = px0 - 1 + c;
            rlo[e0] = (pc * 8 + ch8) * 8;
            if (gy >= 0 && gy < HW && gx >= 0 && gx < HW)
                rpb[e0] = (gy * HW + gx) * 64 + ch8 * 8;
        }
    }
    const int yidx = (py0 + ((tid >> 3) >> 3)) * HW + px0 + ((tid >> 3) & 7);

    const _Float16* wbase = wlds + (fam ? 23040 : 0) + lane * 8;
    const _Float16* bb    = sbuf + fam * 9792 + l5 * 4896;

    half8 vv[3];
    __syncthreads();

    #pragma unroll 1
    for (int tau = 0; tau <= 32; ++tau) {
        const _Float16* xt = xh + (size_t)tau * NPIX * 8;
        _Float16* h0p  = (tau & 1) ? h0b : h0a;   // h0(tau-1)
        _Float16* h0w  = (tau & 1) ? h0a : h0b;   // h0(tau)
        _Float16* h1p2 = (tau & 1) ? h1a : h1b;   // h1(tau-2)
        _Float16* h1w  = (tau & 1) ? h1b : h1a;   // h1(tau-1)
        const bool a0 = (tau < 32);
        const bool a1 = (tau >= 1);
        const bool ar = (tau >= 2);

        // pre-issue readout(tau-2) halo loads (hide RTT under the kc loop)
        half8 rv0 = {0,0,0,0,0,0,0,0}, rv1 = {0,0,0,0,0,0,0,0};
        if (ar && tid < 512) {
            if (rpb[0] >= 0) rv0 = ld_coh(h1p2 + rpb[0]);
            if (rpb[1] >= 0) rv1 = ld_coh(h1p2 + rpb[1]);
        }

        auto stage_load = [&](int kc) {
            #pragma unroll
            for (int e0 = 0; e0 < 3; ++e0) {
                half8 v = {0, 0, 0, 0, 0, 0, 0, 0};
                const int pb = spb[e0];
                if (slo[e0] >= 0 && pb >= 0) {
                    if (fl[e0] == 0) {
                        if (a0 && kc < 5) {
                            if (kc == 0) { if (ch16 == 0) v = *(const half8*)(xt + (pb >> 3)); }
                            else v = ld_coh(h0p + pb + (kc - 1) * 16);
                        }
                    } else if (a1) {
                        v = (kc < 4) ? ld_coh(h0p + pb + kc * 16)
                                     : ld_coh(h1p2 + pb + (kc - 4) * 16);
                    }
                }
                vv[e0] = v;
            }
        };
        auto stage_write = [&]() {
            #pragma unroll
            for (int e0 = 0; e0 < 3; ++e0)
                if (slo[e0] >= 0) *(half8*)(sbuf + slo[e0]) = vv[e0];
        };

        floatx16 acc[2];
        #pragma unroll
        for (int p_ = 0; p_ < 2; ++p_)
            #pragma unroll
            for (int i = 0; i < 16; ++i) acc[p_][i] = 0.0f;

        stage_load(0);
        stage_write();
        __syncthreads();

        #pragma unroll 1
        for (int kc = 0; kc < 8; ++kc) {
            if (kc < 7) stage_load(kc + 1);
            if (fam ? a1 : (a0 && kc < 5)) {
                const _Float16* wk = wbase + (size_t)(kc * 9) * 512;
                half8 bufA[3], bufB[3];
                #pragma unroll
                for (int d = 0; d < 3; ++d) {
                    bufA[d] = *(const half8*)(bb + ((r0    ) * 34 + cl + d) * 8);
                    bufB[d] = *(const half8*)(bb + ((r0 + 1) * 34 + cl + d) * 8);
                }
                #pragma unroll
                for (int dx = 0; dx < 3; ++dx) {       // dy=0: rows r0 / r0+1
                    half8 a = *(const half8*)(wk + dx * 512);
                    acc[0] = __builtin_amdgcn_mfma_f32_32x32x16_f16(a, bufA[dx], acc[0], 0, 0, 0);
                    acc[1] = __builtin_amdgcn_mfma_f32_32x32x16_f16(a, bufB[dx], acc[1], 0, 0, 0);
                }
                #pragma unroll
                for (int d = 0; d < 3; ++d)
                    bufA[d] = *(const half8*)(bb + ((r0 + 2) * 34 + cl + d) * 8);
                #pragma unroll
                for (int dx = 0; dx < 3; ++dx) {       // dy=1: rows r0+1 / r0+2
                    half8 a = *(const half8*)(wk + (3 + dx) * 512);
                    acc[0] = __builtin_amdgcn_mfma_f32_32x32x16_f16(a, bufB[dx], acc[0], 0, 0, 0);
                    acc[1] = __builtin_amdgcn_mfma_f32_32x32x16_f16(a, bufA[dx], acc[1], 0, 0, 0);
                }
                #pragma unroll
                for (int d = 0; d < 3; ++d)
                    bufB[d] = *(const half8*)(bb + ((r0 + 3) * 34 + cl + d) * 8);
                #pragma unroll
                for (int dx = 0; dx < 3; ++dx) {       // dy=2: rows r0+2 / r0+3
                    half8 a = *(const half8*)(wk + (6 + dx) * 512);
                    acc[0] = __builtin_amdgcn_mfma_f32_32x32x16_f16(a, bufA[dx], acc[0], 0, 0, 0);
                    acc[1] = __builtin_amdgcn_mfma_f32_32x32x16_f16(a, bufB[dx], acc[1], 0, 0, 0);
                }
            }
            __syncthreads();                    // MFMA reads of slice kc done
            if (kc < 7) {
                stage_write();                  // slice kc+1 into the buffer
                __syncthreads();                // visible before MFMA(kc+1)
            }
        }

        // Epilogue (per family). C/D: col=lane&31 -> px col; reg r=g*4+j ->
        // gate g, hid s*8+4*l5+j. fam0 -> h0(tau), fam1 -> h1(tau-1).
        if (fam ? a1 : a0) {
            _Float16* hO = fam ? h1w : h0w;
            #pragma unroll
            for (int pos = 0; pos < 2; ++pos) {
                const int px = (y0 + r0 + pos) * HW + x0 + cl;
                half4 hn;
                #pragma unroll
                for (int j = 0; j < 4; ++j) {
                    const int bo = fam * 32 + 4 * l5 + j;
                    float iv = sigf(acc[pos][     j] + blds[bo]);
                    float fv = sigf(acc[pos][ 4 + j] + blds[bo + 8]);
                    float ov = sigf(acc[pos][ 8 + j] + blds[bo + 16]);
                    float gv = tanhf_(acc[pos][12 + j] + blds[bo + 24]);
                    float cv = fv * cr[pos][j] + iv * gv;
                    cr[pos][j] = cv;
                    hn[j] = (_Float16)(ov * tanhf_(cv));
                }
                st_coh8(hO + (size_t)px * 64 + s * 8 + 4 * l5, hn);
            }
        }

        // readout(tau-2) by fam0 (stages into sbuf slice-0 region, now dead)
        if (ar) {
            if (tid < 512) {
                if (rlo[0] >= 0) *(half8*)(sbuf + rlo[0]) = rv0;
                if (rlo[1] >= 0) *(half8*)(sbuf + rlo[1]) = rv1;
            }
            __syncthreads();
            if (tid < 512) {
                const int sub = tid & 7;
                const int p   = tid >> 3;
                const int pr  = p >> 3, pcc = p & 7;
                float sacc = 0.0f;
                #pragma unroll
                for (int dy = 0; dy < 3; ++dy)
                    #pragma unroll
                    for (int dx = 0; dx < 3; ++dx) {
                        int pc = (pr + dy) * 10 + (pcc + dx);
                        half8 hv = *(const half8*)(sbuf + ((size_t)pc * 8 + sub) * 8);
                        int tap = dy * 3 + dx;
                        #pragma unroll
                        for (int j = 0; j < 8; ++j)
                            sacc += wl[(sub * 8 + j) * 9 + tap] * (float)hv[j];
                    }
                sacc += __shfl_xor(sacc, 1);
                sacc += __shfl_xor(sacc, 2);
                sacc += __shfl_xor(sacc, 4);
                if (sub == 0) st_coh4(y + (size_t)(tau - 2) * NPIX + yidx, sacc + brv);
            }
        }

        group_sync(gcnt, g, ggy, ggx, (unsigned)(tau + 1));
    }

    // final readout(31): h1(31) lives in h1a (31 odd)
    {
        half8 rv0 = {0,0,0,0,0,0,0,0}, rv1 = {0,0,0,0,0,0,0,0};
        if (tid < 512) {
            if (rpb[0] >= 0) rv0 = ld_coh(h1a + rpb[0]);
            if (rpb[1] >= 0) rv1 = ld_coh(h1a + rpb[1]);
            if (rlo[0] >= 0) *(half8*)(sbuf + rlo[0]) = rv0;
            if (rlo[1] >= 0) *(half8*)(sbuf + rlo[1]) = rv1;
        }
        __syncthreads();
        if (tid < 512) {
            const int sub = tid & 7;
            const int p   = tid >> 3;
            const int pr  = p >> 3, pcc = p & 7;
            float sacc = 0.0f;
            #pragma unroll
            for (int dy = 0; dy < 3; ++dy)
                #pragma unroll
                for (int dx = 0; dx < 3; ++dx) {
                    int pc = (pr + dy) * 10 + (pcc + dx);
                    half8 hv = *(const half8*)(sbuf + ((size_t)pc * 8 + sub) * 8);
                    int tap = dy * 3 + dx;
                    #pragma unroll
                    for (int j = 0; j < 8; ++j)
                        sacc += wl[(sub * 8 + j) * 9 + tap] * (float)hv[j];
                }
            sacc += __shfl_xor(sacc, 1);
            sacc += __shfl_xor(sacc, 2);
            sacc += __shfl_xor(sacc, 4);
            if (sub == 0) st_coh4(y + (size_t)31 * NPIX + yidx, sacc + brv);
        }
    }
}

// ---------------------------------------------------------------------------
// Weight repack: W [256][CIN_W][3][3] fp32 -> WpG [8 s][cell][kc][tap][512] fp16.
// A row rr (=lane&31): gate = rr>>3, hid = s*8 + (rr&7); k = kc*16 + (l>>5)*8 + j.
// ---------------------------------------------------------------------------
__global__ void pack_w(const float* __restrict__ W, _Float16* __restrict__ Wp,
                       int NKC, int CIN_W, int cell1, int base, int total)
{
    int idx = blockIdx.x * 256 + threadIdx.x;
    if (idx >= total) return;
    int j = idx & 7, l = (idx >> 3) & 63;
    int rest = idx >> 9;
    int tap = rest % 9;
    int kt  = rest / 9;
    int kc = kt % NKC, s = kt / NKC;
    int rr = l & 31, l5 = l >> 5;
    int o = (rr >> 3) * 64 + s * 8 + (rr & 7);
    int k = kc * 16 + l5 * 8 + j;
    int cin = cell1 ? ((k < 4) ? k : ((k >= 16 && k < 80) ? k - 12 : -1)) : k;
    float v = (cin >= 0) ? W[((size_t)o * CIN_W + cin) * 9 + tap] : 0.0f;
    Wp[(size_t)s * 59904 + base + (size_t)(kc * 9 + tap) * 512 + l * 8 + j] = (_Float16)v;
}

// x [32][4][128][128] fp32 -> xh [32][px][8] fp16 (ch 0-3 real, 4-7 zero)
__global__ void xconv(const float* __restrict__ x, _Float16* __restrict__ xh)
{
    int idx = blockIdx.x * 256 + threadIdx.x;       // 524288
    int t = idx >> 14, px = idx & 16383;
    const float* xs = x + (size_t)t * 4 * NPIX + px;
    half8 v = {0, 0, 0, 0, 0, 0, 0, 0};
    v[0] = (_Float16)xs[0];
    v[1] = (_Float16)xs[NPIX];
    v[2] = (_Float16)xs[2 * NPIX];
    v[3] = (_Float16)xs[3 * NPIX];
    *(half8*)(xh + (size_t)idx * 8) = v;
}

extern "C" void kernel_launch(void* const* d_in, const int* in_sizes, int n_in,
                              void* d_out, int out_size, void* d_ws, size_t ws_size,
                              hipStream_t stream)
{
    const float* x  = (const float*)d_in[0];
    const float* W0 = (const float*)d_in[1];
    const float* b0 = (const float*)d_in[2];
    const float* W1 = (const float*)d_in[3];
    const float* b1 = (const float*)d_in[4];
    const float* Wr = (const float*)d_in[5];
    const float* br = (const float*)d_in[6];
    float* y = (float*)d_out;

    char* ws = (char*)d_ws;
    _Float16* h0a = (_Float16*)(ws);                    // 2 MB (zeroed: h0(-1))
    _Float16* h1a = (_Float16*)(ws + (2u << 20));       // 2 MB (zeroed: h1(-1))
    _Float16* h0b = (_Float16*)(ws + (4u << 20));       // 2 MB
    _Float16* h1b = (_Float16*)(ws + (6u << 20));       // 2 MB
    _Float16* xh  = (_Float16*)(ws + (8u << 20));       // 8 MB
    _Float16* WpG = (_Float16*)(ws + (16u << 20));      // 936 KB
    unsigned* cnt = (unsigned*)(ws + (17u << 20));      // 32 group counters, 64B each

    // zero t=-1 recurrent state (h0a, h1a) + group counters
    hipMemsetAsync(ws, 0, (4u << 20), stream);
    hipMemsetAsync(cnt, 0, 2048, stream);

    pack_w<<<dim3((184320 + 255) / 256), 256, 0, stream>>>(W0, WpG, 5, 68, 1, 0, 184320);
    pack_w<<<dim3((294912 + 255) / 256), 256, 0, stream>>>(W1, WpG, 8, 128, 0, 23040, 294912);
    xconv<<<dim3(2048), 256, 0, stream>>>(x, xh);

    hipFuncSetAttribute(reinterpret_cast<const void*>(mega),
                        hipFuncAttributeMaxDynamicSharedMemorySize, 161536);
    mega<<<dim3(256), 1024, 161536, stream>>>(xh, WpG, b0, b1, Wr, br,
                                              h0a, h0b, h1a, h1b, y, cnt);
}

// Round 20
// 967.934 us; speedup vs baseline: 1.0242x; 1.0242x over previous
//
#include <hip/hip_runtime.h>
#include <cstdint>
#include <cmath>

#define HW 128
#define NPIX (HW * HW)

typedef _Float16 half8 __attribute__((ext_vector_type(8)));
typedef _Float16 half4 __attribute__((ext_vector_type(4)));
typedef float floatx16 __attribute__((ext_vector_type(16)));
typedef unsigned long long u64;

__device__ __forceinline__ float sigf(float x) {
    return __builtin_amdgcn_rcpf(1.0f + __expf(-x));
}
__device__ __forceinline__ float tanhf_(float x) {
    float cx = fminf(fmaxf(x, -20.0f), 20.0f);
    float e2 = __expf(2.0f * cx);
    return (e2 - 1.0f) * __builtin_amdgcn_rcpf(e2 + 1.0f);
}

// Coherent h-load: relaxed agent-scope atomics (sc1 -> IF coherence point).
__device__ __forceinline__ half8 ld_coh(const _Float16* p) {
    union { u64 u[2]; half8 h; } cv;
    cv.u[0] = __hip_atomic_load((const u64*)p,
                                __ATOMIC_RELAXED, __HIP_MEMORY_SCOPE_AGENT);
    cv.u[1] = __hip_atomic_load((const u64*)p + 1,
                                __ATOMIC_RELAXED, __HIP_MEMORY_SCOPE_AGENT);
    return cv.h;
}

// device-coherent write-through stores (visible at IF; no dirty L2 lines)
__device__ __forceinline__ void st_coh8(_Float16* p, half4 v) {
    asm volatile("global_store_dwordx2 %0, %1, off sc0 sc1"
                 :: "v"(p), "v"(v) : "memory");
}
__device__ __forceinline__ void st_coh4(float* p, float v) {
    asm volatile("global_store_dword %0, %1, off sc0 sc1"
                 :: "v"(p), "v"(v) : "memory");
}

// Neighbor-group sync. 32 groups (8x4 of 16x32-px tiles); 8 blocks/group.
// Arrival: bump gcnt[g] (monotonic, 64B-padded). Wait: lanes 0..8 of wave 0
// poll <=9 Chebyshev-neighbor counters for >= 8k. All relaxed agent atomics;
// vmcnt drain first publishes this block's sc1 h-stores. No fences.
__device__ __forceinline__ void group_sync(unsigned* gcnt, int g,
                                           int gy, int gx, unsigned k)
{
    asm volatile("s_waitcnt vmcnt(0)" ::: "memory");
    __syncthreads();
    const int tid = threadIdx.x;
    if (tid == 0)
        __hip_atomic_fetch_add(gcnt + g * 16, 1u,
                               __ATOMIC_RELAXED, __HIP_MEMORY_SCOPE_AGENT);
    if (tid < 9) {
        int dy = tid / 3 - 1, dx = tid % 3 - 1;
        int gy2 = gy + dy, gx2 = gx + dx;
        if (gy2 >= 0 && gy2 < 8 && gx2 >= 0 && gx2 < 4) {
            const unsigned* p = gcnt + (gy2 * 4 + gx2) * 16;
            while (__hip_atomic_load(p, __ATOMIC_RELAXED,
                                     __HIP_MEMORY_SCOPE_AGENT) < 8u * k)
                __builtin_amdgcn_s_sleep(1);
        }
    }
    __syncthreads();
}

// ---------------------------------------------------------------------------
// kc-split cell phase. Block: group (bid&31) = 16x32 px tile, s = bid>>5.
// 16 waves = 8 row-pairs (wf) x 2 kc-halves (kh). Per superstep j: slot0
// holds slice kc=j (half0), slot1 slice kc=NK0+j (half1); each valid wave
// runs R14's rolling 2-row tap loop (21 LDS reads / 18 MFMAs). After the
// supersteps, half1's fp32 partials are reduced into half0 via sbuf (2
// rounds x 32KB), and half0 runs the LSTM epilogue (owns c).
// ---------------------------------------------------------------------------
template<int NKC, int CELL>
__device__ __forceinline__ void cell_phase(
    const _Float16* __restrict__ xt,    // CELL 0 only: xh [px][8]
    const _Float16* __restrict__ hA,    // CELL0: h0(t-1); CELL1: h0(t)  (coh)
    const _Float16* __restrict__ hB,    // CELL1 only: h1(t-1)           (coh)
    const _Float16* wcell,              // LDS weights for this cell [NKC][9][512]
    const float* blds,                  // LDS bias [2][4 gate][8 hid]
    float (&cr)[2][4],                  // c in registers (half0 threads)
    _Float16* __restrict__ hOut,        // h out [px][64], sc1 stores
    _Float16* sbuf,                     // LDS [2 slot][2 chunk][612][8]
    const int (&spb)[3], const int (&slo)[3],
    const int (&sfl)[3], const int (&sch)[3],
    int y0, int x0, int s, int kh, int wf, int lane)
{
    constexpr int NK0 = (NKC + 1) / 2;          // supersteps
    const int cl = lane & 31, l5 = lane >> 5;
    const int r0 = 2 * wf;
    const int tid = threadIdx.x;

    half8 vv[3];
    auto stage_load = [&](int j) {
        #pragma unroll
        for (int e0 = 0; e0 < 3; ++e0) {
            half8 v = {0, 0, 0, 0, 0, 0, 0, 0};
            if (slo[e0] >= 0) {
                int kc = sfl[e0] ? (NK0 + j) : j;
                if (kc < NKC && spb[e0] >= 0) {
                    if (CELL == 0) {
                        if (kc == 0) { if (sch[e0] == 0) v = *(const half8*)(xt + (spb[e0] >> 3)); }
                        else v = ld_coh(hA + spb[e0] + (kc - 1) * 16);
                    } else {
                        v = (kc < 4) ? ld_coh(hA + spb[e0] + kc * 16)
                                     : ld_coh(hB + spb[e0] + (kc - 4) * 16);
                    }
                }
            }
            vv[e0] = v;
        }
    };
    auto stage_write = [&](int j) {
        #pragma unroll
        for (int e0 = 0; e0 < 3; ++e0) {
            if (slo[e0] >= 0) {
                int kc = sfl[e0] ? (NK0 + j) : j;
                if (kc < NKC) *(half8*)(sbuf + slo[e0]) = vv[e0];
            }
        }
    };

    floatx16 acc[2];
    #pragma unroll
    for (int p_ = 0; p_ < 2; ++p_)
        #pragma unroll
        for (int i = 0; i < 16; ++i) acc[p_][i] = 0.0f;

    stage_load(0);
    __syncthreads();                       // sbuf free from previous phase
    stage_write(0);
    __syncthreads();

    const _Float16* bb = sbuf + kh * 9792 + l5 * 4896;

    #pragma unroll
    for (int j = 0; j < NK0; ++j) {
        if (j + 1 < NK0) stage_load(j + 1);

        const int kc = kh ? (NK0 + j) : j;
        if (kc < NKC) {
            const _Float16* wk = wcell + (size_t)(kc * 9) * 512 + lane * 8;
            half8 bufA[3], bufB[3];
            #pragma unroll
            for (int d = 0; d < 3; ++d) {
                bufA[d] = *(const half8*)(bb + ((r0    ) * 34 + cl + d) * 8);
                bufB[d] = *(const half8*)(bb + ((r0 + 1) * 34 + cl + d) * 8);
            }
            #pragma unroll
            for (int dx = 0; dx < 3; ++dx) {       // dy=0: rows r0 / r0+1
                half8 a = *(const half8*)(wk + dx * 512);
                acc[0] = __builtin_amdgcn_mfma_f32_32x32x16_f16(a, bufA[dx], acc[0], 0, 0, 0);
                acc[1] = __builtin_amdgcn_mfma_f32_32x32x16_f16(a, bufB[dx], acc[1], 0, 0, 0);
            }
            #pragma unroll
            for (int d = 0; d < 3; ++d)
                bufA[d] = *(const half8*)(bb + ((r0 + 2) * 34 + cl + d) * 8);
            #pragma unroll
            for (int dx = 0; dx < 3; ++dx) {       // dy=1: rows r0+1 / r0+2
                half8 a = *(const half8*)(wk + (3 + dx) * 512);
                acc[0] = __builtin_amdgcn_mfma_f32_32x32x16_f16(a, bufB[dx], acc[0], 0, 0, 0);
                acc[1] = __builtin_amdgcn_mfma_f32_32x32x16_f16(a, bufA[dx], acc[1], 0, 0, 0);
            }
            #pragma unroll
            for (int d = 0; d < 3; ++d)
                bufB[d] = *(const half8*)(bb + ((r0 + 3) * 34 + cl + d) * 8);
            #pragma unroll
            for (int dx = 0; dx < 3; ++dx) {       // dy=2: rows r0+2 / r0+3
                half8 a = *(const half8*)(wk + (6 + dx) * 512);
                acc[0] = __builtin_amdgcn_mfma_f32_32x32x16_f16(a, bufA[dx], acc[0], 0, 0, 0);
                acc[1] = __builtin_amdgcn_mfma_f32_32x32x16_f16(a, bufB[dx], acc[1], 0, 0, 0);
            }
        }
        __syncthreads();                   // all reads of this superstep done
        if (j + 1 < NK0) {
            stage_write(j + 1);
            __syncthreads();               // next slices visible
        }
    }

    // ---- reduction: half1 partials -> half0 (fp32, 2 rounds via sbuf) ----
    float* xch = (float*)sbuf;
    #pragma unroll
    for (int pos = 0; pos < 2; ++pos) {
        if (kh == 1) {
            float* q = xch + (tid - 512) * 16;
            #pragma unroll
            for (int i = 0; i < 16; i += 4)
                *(float4*)(q + i) = make_float4(acc[pos][i], acc[pos][i + 1],
                                                acc[pos][i + 2], acc[pos][i + 3]);
        }
        __syncthreads();
        if (kh == 0) {
            const float* q = xch + tid * 16;
            #pragma unroll
            for (int i = 0; i < 16; i += 4) {
                float4 p4 = *(const float4*)(q + i);
                acc[pos][i] += p4.x; acc[pos][i + 1] += p4.y;
                acc[pos][i + 2] += p4.z; acc[pos][i + 3] += p4.w;
            }
        }
        __syncthreads();
    }

    // ---- epilogue (half0 only). C/D: col=lane&31 -> px col;
    //      reg r=g*4+j -> gate g, hid s*8+4*l5+j. ----
    if (kh == 0) {
        #pragma unroll
        for (int pos = 0; pos < 2; ++pos) {
            const int px = (y0 + r0 + pos) * HW + x0 + cl;
            half4 hn;
            #pragma unroll
            for (int j = 0; j < 4; ++j) {
                const int bo = CELL * 32 + 4 * l5 + j;
                float iv = sigf(acc[pos][     j] + blds[bo]);
                float fv = sigf(acc[pos][ 4 + j] + blds[bo + 8]);
                float ov = sigf(acc[pos][ 8 + j] + blds[bo + 16]);
                float gv = tanhf_(acc[pos][12 + j] + blds[bo + 24]);
                float cv = fv * cr[pos][j] + iv * gv;
                cr[pos][j] = cv;
                hn[j] = (_Float16)(ov * tanhf_(cv));
            }
            st_coh8(hOut + (size_t)px * 64 + s * 8 + 4 * l5, hn);
        }
    }
}

// Readout 64->1 conv. Block s handles patch s (8x8) of its group tile.
// rv = the pre-issued halo load (800 elems, 1/thread at 1024 threads).
__device__ __forceinline__ void readout_phase(
    half8 rv, const float* wl, float brv,
    float* __restrict__ yout, _Float16* sbuf, int rlo, int yidx)
{
    const int tid = threadIdx.x;
    __syncthreads();                       // prior sbuf users done
    if (rlo >= 0) *(half8*)(sbuf + rlo) = rv;
    __syncthreads();

    if (tid < 512) {
        const int sub = tid & 7;
        const int p   = tid >> 3;
        const int pr  = p >> 3, pcc = p & 7;
        float sacc = 0.0f;
        #pragma unroll
        for (int dy = 0; dy < 3; ++dy)
            #pragma unroll
            for (int dx = 0; dx < 3; ++dx) {
                int pc = (pr + dy) * 10 + (pcc + dx);
                half8 hv = *(const half8*)(sbuf + ((size_t)pc * 8 + sub) * 8);
                int tap = dy * 3 + dx;
                #pragma unroll
                for (int j = 0; j < 8; ++j)
                    sacc += wl[(sub * 8 + j) * 9 + tap] * (float)hv[j];
            }
        sacc += __shfl_xor(sacc, 1);
        sacc += __shfl_xor(sacc, 2);
        sacc += __shfl_xor(sacc, 4);
        if (sub == 0) st_coh4(yout + yidx, sacc + brv);
    }
}

// LDS map (dynamic, 161536 B): wlds @0 (119808), sbuf @119808 (39168),
// wl @158976 (2304), blds @161280 (256).
// 256 blocks x 1024 thr (16 waves = 8 row-pairs x 2 kc-halves). Per t:
//   cell1(t); GROUP_SYNC; issue rv(t-1); cell2(t); readout(t-1).
__global__ __launch_bounds__(1024, 4)
void mega(const _Float16* __restrict__ xh, const _Float16* __restrict__ WpG,
          const float* __restrict__ b0g, const float* __restrict__ b1g,
          const float* __restrict__ Wr, const float* __restrict__ br,
          _Float16* __restrict__ h0a, _Float16* __restrict__ h0b,
          _Float16* __restrict__ h1a, _Float16* __restrict__ h1b,
          float* __restrict__ y, unsigned* gcnt)
{
    extern __shared__ __align__(16) char dyn[];
    _Float16* wlds = (_Float16*)dyn;
    _Float16* sbuf = (_Float16*)(dyn + 119808);
    float*    wl   = (float*)(dyn + 158976);
    float*    blds = (float*)(dyn + 161280);

    const int tid = threadIdx.x;
    const int bid = blockIdx.x;
    const int s = bid >> 5, g = bid & 31;
    const int ggy = g >> 2, ggx = g & 3;
    const int y0 = ggy * 16, x0 = ggx * 32;

    const int lane = tid & 63;
    const int wv   = tid >> 6;
    const int kh   = wv >> 3;           // kc-half
    const int wf   = wv & 7;            // row-pair

    // one-time: weights (both cells) + readout weights + biases into LDS
    const half8* wsrc = (const half8*)(WpG + (size_t)s * 59904);
    for (int i = tid; i < 7488; i += 1024) ((half8*)wlds)[i] = wsrc[i];
    for (int i = tid; i < 576; i += 1024) wl[i] = Wr[i];
    if (tid < 64) {
        int cell = tid >> 5, gj = tid & 31;
        blds[tid] = (cell ? b1g : b0g)[(gj >> 3) * 64 + s * 8 + (gj & 7)];
    }
    const float brv = br[0];
    float c0r[2][4] = {{0, 0, 0, 0}, {0, 0, 0, 0}};
    float c1r[2][4] = {{0, 0, 0, 0}, {0, 0, 0, 0}};

    // ---- staging precompute: 2448 elems = 2 slots x 612 px x 2 chunks ----
    int spb[3], slo[3], sfl[3], sch[3];
    #pragma unroll
    for (int e0 = 0; e0 < 3; ++e0) {
        int e = tid + e0 * 1024;
        spb[e0] = -1; slo[e0] = -1; sfl[e0] = 0; sch[e0] = 0;
        if (e < 2448) {
            int f  = (e >= 1224) ? 1 : 0;
            int es = e - f * 1224;
            int pc = es >> 1, ch = es & 1;
            int r = pc / 34, c = pc - r * 34;
            int gy = y0 - 1 + r, gx = x0 - 1 + c;
            slo[e0] = f * 9792 + ch * 4896 + pc * 8;
            sfl[e0] = f; sch[e0] = ch;
            if (gy >= 0 && gy < HW && gx >= 0 && gx < HW)
                spb[e0] = (gy * HW + gx) * 64 + ch * 8;
        }
    }
    // readout staging (800 elems: 10x10 px halo x 8 chunks), 1/thread
    const int ch8 = tid & 7;
    const int py0 = y0 + (s >> 2) * 8, px0 = x0 + (s & 3) * 8;
    int rpb = -1, rlo = -1;
    if (tid < 800) {
        int pc = tid >> 3;
        int r = pc / 10, c = pc - r * 10;
        int gy = py0 - 1 + r, gx = px0 - 1 + c;
        rlo = (pc * 8 + ch8) * 8;
        if (gy >= 0 && gy < HW && gx >= 0 && gx < HW)
            rpb = (gy * HW + gx) * 64 + ch8 * 8;
    }
    const int yidx = (py0 + ((tid >> 3) >> 3)) * HW + px0 + ((tid >> 3) & 7);

    __syncthreads();

    #pragma unroll 1
    for (int t = 0; t < 32; ++t) {
        const _Float16* xt = xh + (size_t)t * NPIX * 8;
        const _Float16* h0r = (t & 1) ? h0b : h0a;
        _Float16*       h0w = (t & 1) ? h0a : h0b;
        const _Float16* h1r = (t & 1) ? h1b : h1a;
        _Float16*       h1w = (t & 1) ? h1a : h1b;

        cell_phase<5, 0>(xt, h0r, nullptr, wlds, blds, c0r, h0w, sbuf,
                         spb, slo, sfl, sch, y0, x0, s, kh, wf, lane);
        group_sync(gcnt, g, ggy, ggx, (unsigned)(t + 1));

        // issue readout(t-1) halo load now: IF RTT hides under cell2
        half8 rv = {0, 0, 0, 0, 0, 0, 0, 0};
        if (t > 0 && rpb >= 0) rv = ld_coh(h1r + rpb);

        cell_phase<8, 1>(nullptr, h0w, h1r, wlds + 23040, blds, c1r, h1w, sbuf,
                         spb, slo, sfl, sch, y0, x0, s, kh, wf, lane);

        if (t > 0)
            readout_phase(rv, wl, brv, y + (size_t)(t - 1) * NPIX, sbuf,
                          rlo, yidx);
    }
    group_sync(gcnt, g, ggy, ggx, 33u);
    {
        half8 rv = {0, 0, 0, 0, 0, 0, 0, 0};
        if (rpb >= 0) rv = ld_coh(h1a + rpb);
        readout_phase(rv, wl, brv, y + (size_t)31 * NPIX, sbuf, rlo, yidx);
    }
}

// ---------------------------------------------------------------------------
// Weight repack: W [256][CIN_W][3][3] fp32 -> WpG [8 s][cell][kc][tap][512] fp16.
// A row rr (=lane&31): gate = rr>>3, hid = s*8 + (rr&7); k = kc*16 + (l>>5)*8 + j.
// ---------------------------------------------------------------------------
__global__ void pack_w(const float* __restrict__ W, _Float16* __restrict__ Wp,
                       int NKC, int CIN_W, int cell1, int base, int total)
{
    int idx = blockIdx.x * 256 + threadIdx.x;
    if (idx >= total) return;
    int j = idx & 7, l = (idx >> 3) & 63;
    int rest = idx >> 9;
    int tap = rest % 9;
    int kt  = rest / 9;
    int kc = kt % NKC, s = kt / NKC;
    int rr = l & 31, l5 = l >> 5;
    int o = (rr >> 3) * 64 + s * 8 + (rr & 7);
    int k = kc * 16 + l5 * 8 + j;
    int cin = cell1 ? ((k < 4) ? k : ((k >= 16 && k < 80) ? k - 12 : -1)) : k;
    float v = (cin >= 0) ? W[((size_t)o * CIN_W + cin) * 9 + tap] : 0.0f;
    Wp[(size_t)s * 59904 + base + (size_t)(kc * 9 + tap) * 512 + l * 8 + j] = (_Float16)v;
}

// x [32][4][128][128] fp32 -> xh [32][px][8] fp16 (ch 0-3 real, 4-7 zero)
__global__ void xconv(const float* __restrict__ x, _Float16* __restrict__ xh)
{
    int idx = blockIdx.x * 256 + threadIdx.x;       // 524288
    int t = idx >> 14, px = idx & 16383;
    const float* xs = x + (size_t)t * 4 * NPIX + px;
    half8 v = {0, 0, 0, 0, 0, 0, 0, 0};
    v[0] = (_Float16)xs[0];
    v[1] = (_Float16)xs[NPIX];
    v[2] = (_Float16)xs[2 * NPIX];
    v[3] = (_Float16)xs[3 * NPIX];
    *(half8*)(xh + (size_t)idx * 8) = v;
}

extern "C" void kernel_launch(void* const* d_in, const int* in_sizes, int n_in,
                              void* d_out, int out_size, void* d_ws, size_t ws_size,
                              hipStream_t stream)
{
    const float* x  = (const float*)d_in[0];
    const float* W0 = (const float*)d_in[1];
    const float* b0 = (const float*)d_in[2];
    const float* W1 = (const float*)d_in[3];
    const float* b1 = (const float*)d_in[4];
    const float* Wr = (const float*)d_in[5];
    const float* br = (const float*)d_in[6];
    float* y = (float*)d_out;

    char* ws = (char*)d_ws;
    _Float16* h0a = (_Float16*)(ws);                    // 2 MB (zeroed)
    _Float16* h1a = (_Float16*)(ws + (2u << 20));       // 2 MB (zeroed)
    _Float16* h0b = (_Float16*)(ws + (4u << 20));       // 2 MB
    _Float16* h1b = (_Float16*)(ws + (6u << 20));       // 2 MB
    _Float16* xh  = (_Float16*)(ws + (8u << 20));       // 8 MB
    _Float16* WpG = (_Float16*)(ws + (16u << 20));      // 936 KB
    unsigned* cnt = (unsigned*)(ws + (17u << 20));      // 32 group counters, 64B each

    // zero t=0 recurrent state (h0a, h1a) + group counters
    hipMemsetAsync(ws, 0, (4u << 20), stream);
    hipMemsetAsync(cnt, 0, 2048, stream);

    pack_w<<<dim3((184320 + 255) / 256), 256, 0, stream>>>(W0, WpG, 5, 68, 1, 0, 184320);
    pack_w<<<dim3((294912 + 255) / 256), 256, 0, stream>>>(W1, WpG, 8, 128, 0, 23040, 294912);
    xconv<<<dim3(2048), 256, 0, stream>>>(x, xh);

    hipFuncSetAttribute(reinterpret_cast<const void*>(mega),
                        hipFuncAttributeMaxDynamicSharedMemorySize, 161536);
    mega<<<dim3(256), 1024, 161536, stream>>>(xh, WpG, b0, b1, Wr, br,
                                              h0a, h0b, h1a, h1b, y, cnt);
}

// Round 21
// 823.617 us; speedup vs baseline: 1.2037x; 1.1752x over previous
//
#include <hip/hip_runtime.h>
#include <cstdint>
#include <cmath>

#define HW 128
#define NPIX (HW * HW)

typedef _Float16 half8 __attribute__((ext_vector_type(8)));
typedef _Float16 half4 __attribute__((ext_vector_type(4)));
typedef float floatx16 __attribute__((ext_vector_type(16)));
typedef unsigned long long u64;

__device__ __forceinline__ float sigf(float x) {
    return __builtin_amdgcn_rcpf(1.0f + __expf(-x));
}
__device__ __forceinline__ float tanhf_(float x) {
    float cx = fminf(fmaxf(x, -20.0f), 20.0f);
    float e2 = __expf(2.0f * cx);
    return (e2 - 1.0f) * __builtin_amdgcn_rcpf(e2 + 1.0f);
}

// Coherent h-load: relaxed agent-scope atomics (sc1 -> IF coherence point).
__device__ __forceinline__ half8 ld_coh(const _Float16* p) {
    union { u64 u[2]; half8 h; } cv;
    cv.u[0] = __hip_atomic_load((const u64*)p,
                                __ATOMIC_RELAXED, __HIP_MEMORY_SCOPE_AGENT);
    cv.u[1] = __hip_atomic_load((const u64*)p + 1,
                                __ATOMIC_RELAXED, __HIP_MEMORY_SCOPE_AGENT);
    return cv.h;
}

// device-coherent write-through stores (visible at IF; no dirty L2 lines)
__device__ __forceinline__ void st_coh8(_Float16* p, half4 v) {
    asm volatile("global_store_dwordx2 %0, %1, off sc0 sc1"
                 :: "v"(p), "v"(v) : "memory");
}
__device__ __forceinline__ void st_coh4(float* p, float v) {
    asm volatile("global_store_dword %0, %1, off sc0 sc1"
                 :: "v"(p), "v"(v) : "memory");
}

// Neighbor-group sync. 32 groups (8x4 of 16x32-px tiles); group g exchanges
// halo only with its <=9 Chebyshev neighbors. Arrival: each of 8 blocks in g
// bumps gcnt[g] (monotonic, 64B-padded). Wait: lanes 0..8 of wave 0 poll the
// neighbor counters for >= 8k. All relaxed agent atomics; vmcnt drain first
// publishes this block's sc1 h-stores. No fences, no global coupling.
__device__ __forceinline__ void group_sync(unsigned* gcnt, int g,
                                           int gy, int gx, unsigned k)
{
    asm volatile("s_waitcnt vmcnt(0)" ::: "memory");
    __syncthreads();
    const int tid = threadIdx.x;
    if (tid == 0)
        __hip_atomic_fetch_add(gcnt + g * 16, 1u,
                               __ATOMIC_RELAXED, __HIP_MEMORY_SCOPE_AGENT);
    if (tid < 9) {
        int dy = tid / 3 - 1, dx = tid % 3 - 1;
        int gy2 = gy + dy, gx2 = gx + dx;
        if (gy2 >= 0 && gy2 < 8 && gx2 >= 0 && gx2 < 4) {
            const unsigned* p = gcnt + (gy2 * 4 + gx2) * 16;
            while (__hip_atomic_load(p, __ATOMIC_RELAXED,
                                     __HIP_MEMORY_SCOPE_AGENT) < 8u * k)
                __builtin_amdgcn_s_sleep(1);
        }
    }
    __syncthreads();
}

// ---------------------------------------------------------------------------
// Cell phase. Group (bid&31) = 16x32 px tile; block s = bid>>5 computes gate
// rows [s*32, s*32+32) (all 4 gates of hid s*8..s*8+7) for all 512 px.
// 1024 threads = 16 waves; wave w owns row y0+w x 32 px (one f32x16 acc).
// Weights in LDS. B staged per-kc-slice, double-buffered rolling 2-deep
// (vv[2], low VGPR). h loads coherent (ld_coh). 9 A + 9 B ds_reads per kc.
// ---------------------------------------------------------------------------
template<int NKC, int CELL>
__device__ __forceinline__ void cell_phase(
    const _Float16* __restrict__ xt,    // CELL 0 only: xh [px][8] (cached, L2)
    const _Float16* __restrict__ hA,    // CELL0: h0(t-1); CELL1: h0(t)  (coh)
    const _Float16* __restrict__ hB,    // CELL1 only: h1(t-1)           (coh)
    const _Float16* wlds,               // LDS weight slice [NKC][9][512]
    const float* blds,                  // LDS bias [2][4 gate][8 hid]
    float (&cr)[4],                     // c in registers (this wave's row)
    _Float16* __restrict__ hOut,        // h out [px][64], sc1 stores
    _Float16* sbuf,                     // LDS [2 buf][2 chunk][612][8]
    const int (&spb)[2], const int (&slo)[2], int ch16,
    int y0, int x0, int s)
{
    const int tid  = threadIdx.x;
    const int lane = tid & 63;
    const int w    = tid >> 6;          // wave 0..15 -> tile row
    const int cl   = lane & 31;
    const int l5   = lane >> 5;

    half8 vv[2];
    auto stage_load = [&](int kc) {
        #pragma unroll
        for (int e0 = 0; e0 < 2; ++e0) {
            half8 v = {0, 0, 0, 0, 0, 0, 0, 0};
            const int pb = spb[e0];
            if (pb >= 0) {
                if (CELL == 0) {
                    if (kc == 0) { if (ch16 == 0) v = *(const half8*)(xt + (pb >> 3)); }
                    else v = ld_coh(hA + pb + (kc - 1) * 16);
                } else {
                    v = (kc < 4) ? ld_coh(hA + pb + kc * 16)
                                 : ld_coh(hB + pb + (kc - 4) * 16);
                }
            }
            vv[e0] = v;
        }
    };
    auto stage_write = [&](int b) {
        #pragma unroll
        for (int e0 = 0; e0 < 2; ++e0)
            if (slo[e0] >= 0) *(half8*)(sbuf + b * 9792 + slo[e0]) = vv[e0];
    };

    floatx16 acc;
    #pragma unroll
    for (int i = 0; i < 16; ++i) acc[i] = 0.0f;

    __syncthreads();                       // sbuf reuse safety (prev phase reads)
    stage_load(0);
    stage_write(0);
    __syncthreads();

    #pragma unroll 1
    for (int kc = 0; kc < NKC; ++kc) {
        if (kc + 1 < NKC) stage_load(kc + 1);
        const _Float16* wk = wlds + (size_t)(kc * 9) * 512 + lane * 8;
        const _Float16* bbase = sbuf + ((kc & 1) * 2 + l5) * 4896;
        #pragma unroll
        for (int dy = 0; dy < 3; ++dy)
            #pragma unroll
            for (int dx = 0; dx < 3; ++dx) {
                half8 a = *(const half8*)(wk + (dy * 3 + dx) * 512);
                half8 b = *(const half8*)(bbase + ((w + dy) * 34 + cl + dx) * 8);
                acc = __builtin_amdgcn_mfma_f32_32x32x16_f16(a, b, acc, 0, 0, 0);
            }
        if (kc + 1 < NKC) stage_write((kc + 1) & 1);
        __syncthreads();
    }

    // Epilogue. C/D: col=lane&31 -> px col; reg r=g*4+j -> gate g, hid s*8+4*l5+j.
    const int px = (y0 + w) * HW + x0 + cl;
    half4 hn;
    #pragma unroll
    for (int j = 0; j < 4; ++j) {
        const int bo = CELL * 32 + 4 * l5 + j;
        float iv = sigf(acc[     j] + blds[bo]);
        float fv = sigf(acc[ 4 + j] + blds[bo + 8]);
        float ov = sigf(acc[ 8 + j] + blds[bo + 16]);
        float gv = tanhf_(acc[12 + j] + blds[bo + 24]);
        float cv = fv * cr[j] + iv * gv;
        cr[j] = cv;
        hn[j] = (_Float16)(ov * tanhf_(cv));
    }
    st_coh8(hOut + (size_t)px * 64 + s * 8 + 4 * l5, hn);
}

// Readout 64->1 conv. Block s handles patch s (8x8) of its group tile.
// rv = the pre-issued halo load (800 elems, 1/thread at 1024 threads).
__device__ __forceinline__ void readout_phase(
    half8 rv, const float* wl, float brv,
    float* __restrict__ yout, _Float16* sbuf, int rlo, int yidx)
{
    const int tid = threadIdx.x;
    __syncthreads();                       // prior sbuf reads complete
    if (rlo >= 0) *(half8*)(sbuf + rlo) = rv;
    __syncthreads();

    if (tid < 512) {
        const int sub = tid & 7;
        const int p   = tid >> 3;
        const int pr  = p >> 3, pcc = p & 7;
        float sacc = 0.0f;
        #pragma unroll
        for (int dy = 0; dy < 3; ++dy)
            #pragma unroll
            for (int dx = 0; dx < 3; ++dx) {
                int pc = (pr + dy) * 10 + (pcc + dx);
                half8 hv = *(const half8*)(sbuf + ((size_t)pc * 8 + sub) * 8);
                int tap = dy * 3 + dx;
                #pragma unroll
                for (int j = 0; j < 8; ++j)
                    sacc += wl[(sub * 8 + j) * 9 + tap] * (float)hv[j];
            }
        sacc += __shfl_xor(sacc, 1);
        sacc += __shfl_xor(sacc, 2);
        sacc += __shfl_xor(sacc, 4);
        if (sub == 0) st_coh4(yout + yidx, sacc + brv);
    }
}

// LDS map (dynamic, 161536 B): wlds @0 (119808), sbuf @119808 (39168),
// wl @158976 (2304), blds @161280 (256).
// 256 blocks x 1024 thr (16 waves, 4/SIMD). Schedule per t:
//   cell1(t); GROUP_SYNC; issue rv(t-1); cell2(t); readout(t-1).
__global__ __launch_bounds__(1024, 4)
void mega(const _Float16* __restrict__ xh, const _Float16* __restrict__ WpG,
          const float* __restrict__ b0g, const float* __restrict__ b1g,
          const float* __restrict__ Wr, const float* __restrict__ br,
          _Float16* __restrict__ h0a, _Float16* __restrict__ h0b,
          _Float16* __restrict__ h1a, _Float16* __restrict__ h1b,
          float* __restrict__ y, unsigned* gcnt)
{
    extern __shared__ __align__(16) char dyn[];
    _Float16* wlds = (_Float16*)dyn;
    _Float16* sbuf = (_Float16*)(dyn + 119808);
    float*    wl   = (float*)(dyn + 158976);
    float*    blds = (float*)(dyn + 161280);

    const int tid = threadIdx.x;
    const int bid = blockIdx.x;
    const int s = bid >> 5, g = bid & 31;
    const int ggy = g >> 2, ggx = g & 3;
    const int y0 = ggy * 16, x0 = ggx * 32;

    // one-time: weight slice + readout weights + biases into LDS
    const half8* wsrc = (const half8*)(WpG + (size_t)s * 59904);
    for (int i = tid; i < 7488; i += 1024) ((half8*)wlds)[i] = wsrc[i];
    for (int i = tid; i < 576; i += 1024) wl[i] = Wr[i];
    if (tid < 64) {
        int cell = tid >> 5, gj = tid & 31;
        int gate = gj >> 3, h8 = gj & 7;
        blds[tid] = (cell ? b1g : b0g)[gate * 64 + s * 8 + h8];
    }
    const float brv = br[0];
    float c0r[4] = {0, 0, 0, 0};
    float c1r[4] = {0, 0, 0, 0};

    // ---- t-invariant staging index precompute (1224 elems, 2/thread) ----
    const int ch16 = tid & 1;
    int spb[2], slo[2];
    #pragma unroll
    for (int e0 = 0; e0 < 2; ++e0) {
        int e = tid + e0 * 1024;
        spb[e0] = -1; slo[e0] = -1;
        if (e < 1224) {
            int pc = e >> 1;
            int r = pc / 34, c = pc - r * 34;
            int gy = y0 - 1 + r, gx = x0 - 1 + c;
            slo[e0] = (ch16 * 612 + pc) * 8;
            if (gy >= 0 && gy < HW && gx >= 0 && gx < HW)
                spb[e0] = (gy * HW + gx) * 64 + ch16 * 8;
        }
    }
    // readout staging (800 elems: 10x10 px halo x 8 chunks), 1/thread
    const int ch8 = tid & 7;
    const int py0 = y0 + (s >> 2) * 8, px0 = x0 + (s & 3) * 8;
    int rpb = -1, rlo = -1;
    if (tid < 800) {
        int pc = tid >> 3;
        int r = pc / 10, c = pc - r * 10;
        int gy = py0 - 1 + r, gx = px0 - 1 + c;
        rlo = (pc * 8 + ch8) * 8;
        if (gy >= 0 && gy < HW && gx >= 0 && gx < HW)
            rpb = (gy * HW + gx) * 64 + ch8 * 8;
    }
    const int yidx = (py0 + ((tid >> 3) >> 3)) * HW + px0 + ((tid >> 3) & 7);

    __syncthreads();

    #pragma unroll 1
    for (int t = 0; t < 32; ++t) {
        const _Float16* xt = xh + (size_t)t * NPIX * 8;
        const _Float16* h0r = (t & 1) ? h0b : h0a;
        _Float16*       h0w = (t & 1) ? h0a : h0b;
        const _Float16* h1r = (t & 1) ? h1b : h1a;
        _Float16*       h1w = (t & 1) ? h1a : h1b;

        cell_phase<5, 0>(xt, h0r, nullptr, wlds, blds, c0r, h0w, sbuf,
                         spb, slo, ch16, y0, x0, s);
        group_sync(gcnt, g, ggy, ggx, (unsigned)(t + 1));

        // issue readout(t-1) halo load now: IF RTT hides under cell2
        half8 rv = {0, 0, 0, 0, 0, 0, 0, 0};
        if (t > 0 && rpb >= 0) rv = ld_coh(h1r + rpb);

        cell_phase<8, 1>(nullptr, h0w, h1r, wlds + 23040, blds, c1r, h1w, sbuf,
                         spb, slo, ch16, y0, x0, s);

        if (t > 0)
            readout_phase(rv, wl, brv, y + (size_t)(t - 1) * NPIX, sbuf,
                          rlo, yidx);
    }
    group_sync(gcnt, g, ggy, ggx, 33u);
    {
        half8 rv = {0, 0, 0, 0, 0, 0, 0, 0};
        if (rpb >= 0) rv = ld_coh(h1a + rpb);
        readout_phase(rv, wl, brv, y + (size_t)31 * NPIX, sbuf, rlo, yidx);
    }
}

// ---------------------------------------------------------------------------
// Weight repack: W [256][CIN_W][3][3] fp32 -> WpG [8 s][cell][kc][tap][512] fp16.
// A row rr (=lane&31): gate = rr>>3, hid = s*8 + (rr&7); k = kc*16 + (l>>5)*8 + j.
// ---------------------------------------------------------------------------
__global__ void pack_w(const float* __restrict__ W, _Float16* __restrict__ Wp,
                       int NKC, int CIN_W, int cell1, int base, int total)
{
    int idx = blockIdx.x * 256 + threadIdx.x;
    if (idx >= total) return;
    int j = idx & 7, l = (idx >> 3) & 63;
    int rest = idx >> 9;
    int tap = rest % 9;
    int kt  = rest / 9;
    int kc = kt % NKC, s = kt / NKC;
    int rr = l & 31, l5 = l >> 5;
    int o = (rr >> 3) * 64 + s * 8 + (rr & 7);
    int k = kc * 16 + l5 * 8 + j;
    int cin = cell1 ? ((k < 4) ? k : ((k >= 16 && k < 80) ? k - 12 : -1)) : k;
    float v = (cin >= 0) ? W[((size_t)o * CIN_W + cin) * 9 + tap] : 0.0f;
    Wp[(size_t)s * 59904 + base + (size_t)(kc * 9 + tap) * 512 + l * 8 + j] = (_Float16)v;
}

// x [32][4][128][128] fp32 -> xh [32][px][8] fp16 (ch 0-3 real, 4-7 zero)
__global__ void xconv(const float* __restrict__ x, _Float16* __restrict__ xh)
{
    int idx = blockIdx.x * 256 + threadIdx.x;       // 524288
    int t = idx >> 14, px = idx & 16383;
    const float* xs = x + (size_t)t * 4 * NPIX + px;
    half8 v = {0, 0, 0, 0, 0, 0, 0, 0};
    v[0] = (_Float16)xs[0];
    v[1] = (_Float16)xs[NPIX];
    v[2] = (_Float16)xs[2 * NPIX];
    v[3] = (_Float16)xs[3 * NPIX];
    *(half8*)(xh + (size_t)idx * 8) = v;
}

extern "C" void kernel_launch(void* const* d_in, const int* in_sizes, int n_in,
                              void* d_out, int out_size, void* d_ws, size_t ws_size,
                              hipStream_t stream)
{
    const float* x  = (const float*)d_in[0];
    const float* W0 = (const float*)d_in[1];
    const float* b0 = (const float*)d_in[2];
    const float* W1 = (const float*)d_in[3];
    const float* b1 = (const float*)d_in[4];
    const float* Wr = (const float*)d_in[5];
    const float* br = (const float*)d_in[6];
    float* y = (float*)d_out;

    char* ws = (char*)d_ws;
    _Float16* h0a = (_Float16*)(ws);                    // 2 MB (zeroed)
    _Float16* h1a = (_Float16*)(ws + (2u << 20));       // 2 MB (zeroed)
    _Float16* h0b = (_Float16*)(ws + (4u << 20));       // 2 MB
    _Float16* h1b = (_Float16*)(ws + (6u << 20));       // 2 MB
    _Float16* xh  = (_Float16*)(ws + (8u << 20));       // 8 MB
    _Float16* WpG = (_Float16*)(ws + (16u << 20));      // 936 KB
    unsigned* cnt = (unsigned*)(ws + (17u << 20));      // 32 group counters, 64B each

    // zero t=0 recurrent state (h0a, h1a) + group counters
    hipMemsetAsync(ws, 0, (4u << 20), stream);
    hipMemsetAsync(cnt, 0, 2048, stream);

    pack_w<<<dim3((184320 + 255) / 256), 256, 0, stream>>>(W0, WpG, 5, 68, 1, 0, 184320);
    pack_w<<<dim3((294912 + 255) / 256), 256, 0, stream>>>(W1, WpG, 8, 128, 0, 23040, 294912);
    xconv<<<dim3(2048), 256, 0, stream>>>(x, xh);

    hipFuncSetAttribute(reinterpret_cast<const void*>(mega),
                        hipFuncAttributeMaxDynamicSharedMemorySize, 161536);
    mega<<<dim3(256), 1024, 161536, stream>>>(xh, WpG, b0, b1, Wr, br,
                                              h0a, h0b, h1a, h1b, y, cnt);
}